// Round 4
// baseline (84.221 us; speedup 1.0000x reference)
//
#include <hip/hip_runtime.h>

#define B_ 32
#define C_ 64
#define H_ 96
#define W_ 96
#define P_ 8
#define D_ 256
#define HP 89              // patches per row/col
#define L_ (HP * HP)       // 7921
#define HW (H_ * W_)       // 9216

#define THP 4              // hp rows per GEMM block
#define NROWS (THP + P_ - 1)   // 11 strip rows staged
#define SW 56              // LDS row stride in u32 words; lg*56%32 = {0,24,16,8}
#define COPY 640           // words per parity copy (11*56=616 -> pad to 32-mult)
#define NHPT ((HP + THP - 1) / THP)   // 23

typedef __attribute__((ext_vector_type(8))) short bf16x8;
typedef __attribute__((ext_vector_type(4))) float f32x4;

static __device__ inline unsigned f2bf_u(float f) {
    union { float f; unsigned u; } v; v.f = f;
    return (v.u + 0x7FFFu + ((v.u >> 16) & 1u)) >> 16;   // RNE
}

// ---- Kernel 1: channel mean -> packed bf16, plus W->bf16 in tail blocks ----
__global__ __launch_bounds__(256) void mean_kernel(const float* __restrict__ x,
                                                   unsigned short* __restrict__ xmb,
                                                   const float* __restrict__ Wm,
                                                   unsigned short* __restrict__ Wb) {
    if (blockIdx.x >= (B_ * HW / 4) / 256) {
        int i = (blockIdx.x - (B_ * HW / 4) / 256) * 256 + threadIdx.x;
        if (i < D_ * P_ * P_ / 4) {
            float4 v = ((const float4*)Wm)[i];
            ushort4 o;
            o.x = (unsigned short)f2bf_u(v.x);
            o.y = (unsigned short)f2bf_u(v.y);
            o.z = (unsigned short)f2bf_u(v.z);
            o.w = (unsigned short)f2bf_u(v.w);
            ((ushort4*)Wb)[i] = o;
        }
        return;
    }
    int idx = blockIdx.x * blockDim.x + threadIdx.x;  // over B*HW/4
    int b   = idx / (HW / 4);
    int hw4 = idx % (HW / 4);
    const float4* p = (const float4*)(x + (size_t)b * C_ * HW) + hw4;
    float4 s = make_float4(0.f, 0.f, 0.f, 0.f);
#pragma unroll 16
    for (int c = 0; c < C_; ++c) {
        float4 v = p[(size_t)c * (HW / 4)];
        s.x += v.x; s.y += v.y; s.z += v.z; s.w += v.w;
    }
    const float inv = 1.0f / C_;
    ushort4 o;
    o.x = (unsigned short)f2bf_u(s.x * inv);
    o.y = (unsigned short)f2bf_u(s.y * inv);
    o.z = (unsigned short)f2bf_u(s.z * inv);
    o.w = (unsigned short)f2bf_u(s.w * inv);
    ((ushort4*)xmb)[idx] = o;
}

// ---- Kernel 2: patch GEMM via MFMA, 4 hp rows per block ----
// Block = (hpt, b), 256 threads = 4 waves; wave w owns output cols [w*64, w*64+64).
// LDS: 11-row bf16 strip as two parity-shifted packed-u32 copies so each lane's
// stride-1 sliding window is 4 aligned ds_read_b32.
__global__ __launch_bounds__(256) void gemm_kernel(const unsigned short* __restrict__ xmb,
                                                   const unsigned short* __restrict__ Wb,
                                                   const float* __restrict__ bias,
                                                   float* __restrict__ out) {
    __shared__ unsigned strip[2 * COPY];   // 5120 B
    const int hpt  = blockIdx.x;
    const int b    = blockIdx.y;
    const int hp0  = hpt * THP;
    const int t    = threadIdx.x;
    const int wave = t >> 6;
    const int lane = t & 63;
    const int l15  = lane & 15;
    const int lg   = lane >> 4;
    const int n0   = wave * 64;

    // ---- stage 11 rows; even copy word w = cols(2w,2w+1), odd = cols(2w+1,2w+2)
    const unsigned* xu = (const unsigned*)(xmb + (size_t)b * HW);  // [96][48] words
    for (int i = t; i < NROWS * SW; i += 256) {
        int r = i / SW, w = i - r * SW;
        int g = hp0 + r;
        unsigned u0 = 0u, u1 = 0u;
        if (g < H_ && w < 48) {
            u0 = xu[g * 48 + w];
            if (w + 1 < 48) u1 = xu[g * 48 + w + 1];
        }
        strip[r * SW + w]        = u0;
        strip[COPY + r * SW + w] = (u0 >> 16) | (u1 << 16);
    }

    // ---- B fragments: lane holds B[k..k+7][n], n = n0+nt*16+l15, k = kh*32+lg*8
    bf16x8 bfrag[2][4];
#pragma unroll
    for (int kh = 0; kh < 2; ++kh)
#pragma unroll
        for (int nt = 0; nt < 4; ++nt) {
            int n = n0 + nt * 16 + l15;
            int k = kh * 32 + lg * 8;
            bfrag[kh][nt] = *(const bf16x8*)(Wb + n * 64 + k);
        }
    float bv[4];
#pragma unroll
    for (int nt = 0; nt < 4; ++nt) bv[nt] = bias[n0 + nt * 16 + l15];

    __syncthreads();

    const unsigned* base = strip + (l15 & 1) * COPY + (l15 >> 1);

    for (int lhp = 0; lhp < THP; ++lhp) {
        const int hp = hp0 + lhp;
        if (hp >= HP) break;                       // wave-uniform tail skip

        f32x4 acc[6][4];
#pragma unroll
        for (int nt = 0; nt < 4; ++nt)
#pragma unroll
            for (int mt = 0; mt < 6; ++mt)
                acc[mt][nt] = f32x4{bv[nt], bv[nt], bv[nt], bv[nt]};

#pragma unroll
        for (int kh = 0; kh < 2; ++kh) {
            const int r = lhp + kh * 4 + lg;       // strip row for this lane
            bf16x8 afrag[6];
#pragma unroll
            for (int mt = 0; mt < 6; ++mt) {
                union { uint4 u; bf16x8 s; } a;
                const unsigned* p = base + r * SW + mt * 8;
                a.u.x = p[0]; a.u.y = p[1]; a.u.z = p[2]; a.u.w = p[3];
                afrag[mt] = a.s;
            }
#pragma unroll
            for (int nt = 0; nt < 4; ++nt)
#pragma unroll
                for (int mt = 0; mt < 6; ++mt)
                    acc[mt][nt] = __builtin_amdgcn_mfma_f32_16x16x32_bf16(
                        afrag[mt], bfrag[kh][nt], acc[mt][nt], 0, 0, 0);
        }

        float* outp = out + ((size_t)b * L_ + (size_t)hp * HP) * D_ + n0 + l15;
#pragma unroll
        for (int mt = 0; mt < 6; ++mt)
#pragma unroll
            for (int rg = 0; rg < 4; ++rg) {
                const int wp = mt * 16 + lg * 4 + rg;
                if (wp < HP) {
#pragma unroll
                    for (int nt = 0; nt < 4; ++nt)
                        outp[(size_t)wp * D_ + nt * 16] = acc[mt][nt][rg];
                }
            }
    }
}

extern "C" void kernel_launch(void* const* d_in, const int* in_sizes, int n_in,
                              void* d_out, int out_size, void* d_ws, size_t ws_size,
                              hipStream_t stream) {
    const float* x    = (const float*)d_in[0];
    const float* Wm   = (const float*)d_in[1];
    const float* bias = (const float*)d_in[2];
    float* out = (float*)d_out;

    unsigned short* xmb = (unsigned short*)d_ws;                    // B*HW bf16 = 576 KB
    unsigned short* Wb  = (unsigned short*)((char*)d_ws + (size_t)B_ * HW * 2); // 32 KB

    int nblk = (B_ * HW / 4) / 256 + 16;   // 288 mean blocks + 16 W-convert blocks
    mean_kernel<<<nblk, 256, 0, stream>>>(x, xmb, Wm, Wb);

    dim3 grid(NHPT, B_);
    gemm_kernel<<<grid, 256, 0, stream>>>(xmb, Wb, bias, out);
}